// Round 1
// baseline (132.066 us; speedup 1.0000x reference)
//
#include <hip/hip_runtime.h>

#define BB 4
#define NN 8192
#define ALPHA 5.0f
#define EPSF 1e-12f
#define BLOCK 256
#define QPT 2              // queries per thread
#define QB (BLOCK * QPT)   // 512 queries per block
#define NSEG 8             // ref segments
#define SEG (NN / NSEG)    // 1024 refs per segment
#define TILE 256
#define BIGF 1e30f

__global__ __launch_bounds__(BLOCK) void knn_seg_kernel(
    const float* __restrict__ xyz, float2* __restrict__ pairs) {
  // blockIdx.x = ((b * (NN/QB)) + qchunk) * NSEG + s
  int bid = blockIdx.x;
  int s = bid % NSEG;
  int rem = bid / NSEG;
  int qchunk = rem % (NN / QB);
  int b = rem / (NN / QB);

  const float* xb = xyz + (size_t)b * NN * 3;

  float qx[QPT], qy[QPT], qz[QPT], m1[QPT], m2[QPT];
#pragma unroll
  for (int i = 0; i < QPT; i++) {
    int q = qchunk * QB + threadIdx.x + i * BLOCK;
    qx[i] = xb[3 * q + 0];
    qy[i] = xb[3 * q + 1];
    qz[i] = xb[3 * q + 2];
    m1[i] = BIGF;
    m2[i] = BIGF;
  }

  __shared__ float4 tile[TILE];
  int refBase = s * SEG;

  for (int t = 0; t < SEG; t += TILE) {
    __syncthreads();
    int r = refBase + t + threadIdx.x;
    tile[threadIdx.x] =
        make_float4(xb[3 * r + 0], xb[3 * r + 1], xb[3 * r + 2], 0.0f);
    __syncthreads();

#pragma unroll 8
    for (int j = 0; j < TILE; j++) {
      float4 p = tile[j];
#pragma unroll
      for (int i = 0; i < QPT; i++) {
        float dx = qx[i] - p.x;
        float dy = qy[i] - p.y;
        float dz = qz[i] - p.z;
        float d2 = dx * dx + dy * dy + dz * dz;
        float big = fmaxf(d2, m1[i]);
        m1[i] = fminf(m1[i], d2);
        m2[i] = fminf(m2[i], big);
      }
    }
  }

#pragma unroll
  for (int i = 0; i < QPT; i++) {
    int q = qchunk * QB + threadIdx.x + i * BLOCK;
    pairs[((size_t)b * NN + q) * NSEG + s] = make_float2(m1[i], m2[i]);
  }
}

__device__ __forceinline__ float block_reduce_sum(float v, float* warp_sums) {
  // wave64 shuffle reduce
#pragma unroll
  for (int off = 32; off > 0; off >>= 1) v += __shfl_down(v, off, 64);
  int wid = threadIdx.x >> 6;
  if ((threadIdx.x & 63) == 0) warp_sums[wid] = v;
  __syncthreads();
  float t = 0.0f;
  if (threadIdx.x == 0) {
    for (int w = 0; w < BLOCK / 64; w++) t += warp_sums[w];
  }
  return t;
}

__global__ __launch_bounds__(BLOCK) void merge_kernel(
    const float2* __restrict__ pairs, float* __restrict__ dsum,
    float* __restrict__ batch_sum) {
  int g = blockIdx.x * BLOCK + threadIdx.x;  // global point id over B*N
  int b = g >> 13;                           // N = 8192
  float m1 = BIGF, m2 = BIGF;
#pragma unroll
  for (int s = 0; s < NSEG; s++) {
    float2 p = pairs[(size_t)g * NSEG + s];
    float big = fmaxf(p.x, m1);
    m1 = fminf(m1, p.x);
    m2 = fminf(m2, big);
    big = fmaxf(p.y, m1);
    m1 = fminf(m1, p.y);
    m2 = fminf(m2, big);
  }
  float ds = sqrtf(fmaxf(m1, EPSF)) + sqrtf(fmaxf(m2, EPSF));
  dsum[g] = ds;

  __shared__ float warp_sums[BLOCK / 64];
  float t = block_reduce_sum(ds, warp_sums);
  if (threadIdx.x == 0) atomicAdd(&batch_sum[b], t);
}

__global__ __launch_bounds__(BLOCK) void loss_kernel(
    const float* __restrict__ dsum, const float* __restrict__ batch_sum,
    float* __restrict__ out) {
  int g = blockIdx.x * BLOCK + threadIdx.x;
  int b = g >> 13;
  float ds = dsum[g];
  float avg = batch_sum[b] * (1.0f / NN);
  float v = (ds > avg * ALPHA) ? ds : 0.0f;

  __shared__ float warp_sums[BLOCK / 64];
  float t = block_reduce_sum(v, warp_sums);
  if (threadIdx.x == 0) atomicAdd(out, t);
}

extern "C" void kernel_launch(void* const* d_in, const int* in_sizes, int n_in,
                              void* d_out, int out_size, void* d_ws,
                              size_t ws_size, hipStream_t stream) {
  const float* xyz = (const float*)d_in[0];
  // d_in[1] = nbr_size (== 2), hardcoded.
  float* out = (float*)d_out;

  // ws layout: [0..7] batch_sum (4 used) | [8 .. 8+B*N) dsum | pairs (float2)
  float* batch_sum = (float*)d_ws;
  float* dsum = (float*)d_ws + 8;
  float2* pairs = (float2*)((float*)d_ws + 8 + BB * NN);

  hipMemsetAsync(batch_sum, 0, 8 * sizeof(float), stream);
  hipMemsetAsync(out, 0, sizeof(float), stream);

  int grid1 = BB * (NN / QB) * NSEG;  // 512 blocks
  knn_seg_kernel<<<grid1, BLOCK, 0, stream>>>(xyz, pairs);

  int grid2 = BB * NN / BLOCK;  // 128 blocks
  merge_kernel<<<grid2, BLOCK, 0, stream>>>(pairs, dsum, batch_sum);
  loss_kernel<<<grid2, BLOCK, 0, stream>>>(dsum, batch_sum, out);
}

// Round 2
// 104.382 us; speedup vs baseline: 1.2652x; 1.2652x over previous
//
#include <hip/hip_runtime.h>

#define BB 4
#define NN 8192
#define BN (BB * NN)
#define ALPHA 5.0f
#define EPSF 1e-12f
#define BLOCK 256
#define QPT 2              // queries per thread
#define QB (BLOCK * QPT)   // 512 queries per block
#define BIGF 1e30f

// pairs layout: pairs[s * BN + b*NN + q]  (coalesced for both writer & reader)
template <int NSEG>
__global__ __launch_bounds__(BLOCK) void knn_kernel(
    const float* __restrict__ xyz, float2* __restrict__ pairs) {
  constexpr int SEG = NN / NSEG;
  constexpr int CHUNKS = NN / QB;
  int bid = blockIdx.x;
  int s = bid % NSEG;
  int rem = bid / NSEG;
  int qchunk = rem % CHUNKS;
  int b = rem / CHUNKS;

  const float* xb = xyz + (size_t)b * NN * 3;

  __shared__ float4 tile[SEG];
  int refBase = s * SEG;
#pragma unroll
  for (int r0 = threadIdx.x; r0 < SEG; r0 += BLOCK) {
    int r = refBase + r0;
    tile[r0] = make_float4(xb[3 * r + 0], xb[3 * r + 1], xb[3 * r + 2], 0.0f);
  }

  float qx[QPT], qy[QPT], qz[QPT], m1[QPT], m2[QPT];
#pragma unroll
  for (int i = 0; i < QPT; i++) {
    int q = qchunk * QB + threadIdx.x + i * BLOCK;
    qx[i] = xb[3 * q + 0];
    qy[i] = xb[3 * q + 1];
    qz[i] = xb[3 * q + 2];
    m1[i] = BIGF;
    m2[i] = BIGF;
  }
  __syncthreads();

#pragma unroll 8
  for (int j = 0; j < SEG; j++) {
    float4 p = tile[j];
#pragma unroll
    for (int i = 0; i < QPT; i++) {
      float dx = qx[i] - p.x;
      float dy = qy[i] - p.y;
      float dz = qz[i] - p.z;
      float d2 = fmaf(dx, dx, fmaf(dy, dy, dz * dz));
      float big = fmaxf(d2, m1[i]);
      m1[i] = fminf(m1[i], d2);
      m2[i] = fminf(m2[i], big);
    }
  }

#pragma unroll
  for (int i = 0; i < QPT; i++) {
    int q = qchunk * QB + threadIdx.x + i * BLOCK;
    pairs[(size_t)s * BN + b * NN + q] = make_float2(m1[i], m2[i]);
  }
}

// merge: one thread per point; writes dsum[g] and per-block partial sums.
template <int NSEG>
__global__ __launch_bounds__(BLOCK) void merge_kernel(
    const float2* __restrict__ pairs, float* __restrict__ dsum,
    float* __restrict__ partial) {
  int g = blockIdx.x * BLOCK + threadIdx.x;  // 0 .. BN-1
  float m1 = BIGF, m2 = BIGF;
#pragma unroll
  for (int s = 0; s < NSEG; s++) {
    float2 p = pairs[(size_t)s * BN + g];
    float big = fmaxf(p.x, m1);
    m1 = fminf(m1, p.x);
    m2 = fminf(m2, big);
    big = fmaxf(p.y, m1);
    m1 = fminf(m1, p.y);
    m2 = fminf(m2, big);
  }
  float ds = sqrtf(fmaxf(m1, EPSF)) + sqrtf(fmaxf(m2, EPSF));
  dsum[g] = ds;

  // block reduce (4 waves)
  float v = ds;
#pragma unroll
  for (int off = 32; off > 0; off >>= 1) v += __shfl_down(v, off, 64);
  __shared__ float warp_sums[BLOCK / 64];
  if ((threadIdx.x & 63) == 0) warp_sums[threadIdx.x >> 6] = v;
  __syncthreads();
  if (threadIdx.x == 0) {
    float t = 0.0f;
#pragma unroll
    for (int w = 0; w < BLOCK / 64; w++) t += warp_sums[w];
    partial[blockIdx.x] = t;
  }
}

// loss: single block of 1024 threads. Reduces partials -> batch sums,
// thresholds dsum, writes out[0]. No memsets / atomics needed.
#define LBLK 1024
#define NPART (BN / BLOCK)          // 128
#define PPB (NPART / BB)            // 32 partials per batch
__global__ __launch_bounds__(LBLK) void loss_kernel(
    const float* __restrict__ dsum, const float* __restrict__ partial,
    float* __restrict__ out) {
  __shared__ float s_avg[BB];
  if (threadIdx.x < BB) {
    float t = 0.0f;
    for (int i = 0; i < PPB; i++) t += partial[threadIdx.x * PPB + i];
    s_avg[threadIdx.x] = t * (ALPHA / NN);
  }
  __syncthreads();

  float acc = 0.0f;
#pragma unroll
  for (int it = 0; it < BN / LBLK; it++) {
    int g = it * LBLK + threadIdx.x;
    float ds = dsum[g];
    float thr = s_avg[g >> 13];
    acc += (ds > thr) ? ds : 0.0f;
  }
#pragma unroll
  for (int off = 32; off > 0; off >>= 1) acc += __shfl_down(acc, off, 64);
  __shared__ float warp_sums[LBLK / 64];
  if ((threadIdx.x & 63) == 0) warp_sums[threadIdx.x >> 6] = acc;
  __syncthreads();
  if (threadIdx.x == 0) {
    float t = 0.0f;
#pragma unroll
    for (int w = 0; w < LBLK / 64; w++) t += warp_sums[w];
    out[0] = t;
  }
}

extern "C" void kernel_launch(void* const* d_in, const int* in_sizes, int n_in,
                              void* d_out, int out_size, void* d_ws,
                              size_t ws_size, hipStream_t stream) {
  const float* xyz = (const float*)d_in[0];
  float* out = (float*)d_out;

  size_t need16 = (size_t)16 * BN * sizeof(float2) + BN * sizeof(float) +
                  NPART * sizeof(float);
  if (ws_size >= need16) {
    float2* pairs = (float2*)d_ws;
    float* dsum = (float*)(pairs + (size_t)16 * BN);
    float* partial = dsum + BN;
    int grid1 = BB * (NN / QB) * 16;  // 1024 blocks
    knn_kernel<16><<<grid1, BLOCK, 0, stream>>>(xyz, pairs);
    merge_kernel<16><<<BN / BLOCK, BLOCK, 0, stream>>>(pairs, dsum, partial);
    loss_kernel<<<1, LBLK, 0, stream>>>(dsum, partial, out);
  } else {
    float2* pairs = (float2*)d_ws;
    float* dsum = (float*)(pairs + (size_t)8 * BN);
    float* partial = dsum + BN;
    int grid1 = BB * (NN / QB) * 8;  // 512 blocks
    knn_kernel<8><<<grid1, BLOCK, 0, stream>>>(xyz, pairs);
    merge_kernel<8><<<BN / BLOCK, BLOCK, 0, stream>>>(pairs, dsum, partial);
    loss_kernel<<<1, LBLK, 0, stream>>>(dsum, partial, out);
  }
}

// Round 3
// 99.562 us; speedup vs baseline: 1.3265x; 1.0484x over previous
//
#include <hip/hip_runtime.h>

#define BB 4
#define NN 8192
#define BN (BB * NN)
#define ALPHA 5.0f
#define EPSF 1e-12f
#define BLOCK 256
#define QPT 2              // queries per thread
#define QB (BLOCK * QPT)   // 512 queries per block
#define BIGF 1e30f

// pairs layout: pairs[s * BN + b*NN + q]
template <int NSEG>
__global__ __launch_bounds__(BLOCK, 8) void knn_kernel(
    const float* __restrict__ xyz, float2* __restrict__ pairs) {
  constexpr int SEG = NN / NSEG;
  constexpr int CHUNKS = NN / QB;
  int bid = blockIdx.x;
  int s = bid % NSEG;
  int rem = bid / NSEG;
  int qchunk = rem % CHUNKS;
  int b = rem / CHUNKS;

  const float* xb = xyz + (size_t)b * NN * 3;

  __shared__ float4 tile[SEG];
  int refBase = s * SEG;
  for (int r0 = threadIdx.x; r0 < SEG; r0 += BLOCK) {
    int r = refBase + r0;
    float px = xb[3 * r + 0], py = xb[3 * r + 1], pz = xb[3 * r + 2];
    float pp = fmaf(px, px, fmaf(py, py, pz * pz));
    tile[r0] = make_float4(px, py, pz, pp);
  }

  float qx[QPT], qy[QPT], qz[QPT], qq[QPT], m1[QPT], m2[QPT];
#pragma unroll
  for (int i = 0; i < QPT; i++) {
    int q = qchunk * QB + threadIdx.x + i * BLOCK;
    qx[i] = xb[3 * q + 0];
    qy[i] = xb[3 * q + 1];
    qz[i] = xb[3 * q + 2];
    qq[i] = fmaf(qx[i], qx[i], fmaf(qy[i], qy[i], qz[i] * qz[i]));
    m1[i] = BIGF;
    m2[i] = BIGF;
  }
  __syncthreads();

#pragma unroll 8
  for (int j = 0; j < SEG; j++) {
    float4 p = tile[j];
#pragma unroll
    for (int i = 0; i < QPT; i++) {
      float dot = fmaf(qx[i], p.x, fmaf(qy[i], p.y, qz[i] * p.z));
      float d2 = fmaf(dot, -2.0f, qq[i] + p.w);
      // 2-smallest update, 2 ops: new m2 = median(d2, m1, m2); m1 = min
      float nm2 = __builtin_amdgcn_fmed3f(d2, m1[i], m2[i]);
      m1[i] = fminf(m1[i], d2);
      m2[i] = nm2;
    }
  }

#pragma unroll
  for (int i = 0; i < QPT; i++) {
    int q = qchunk * QB + threadIdx.x + i * BLOCK;
    pairs[(size_t)s * BN + b * NN + q] = make_float2(m1[i], m2[i]);
  }
}

// merge: one thread per point; writes dsum[g] and per-block partial sums.
template <int NSEG>
__global__ __launch_bounds__(BLOCK) void merge_kernel(
    const float2* __restrict__ pairs, float* __restrict__ dsum,
    float* __restrict__ partial) {
  int g = blockIdx.x * BLOCK + threadIdx.x;  // 0 .. BN-1
  float m1 = BIGF, m2 = BIGF;
#pragma unroll 8
  for (int s = 0; s < NSEG; s++) {
    float2 p = pairs[(size_t)s * BN + g];
    float n2 = __builtin_amdgcn_fmed3f(p.x, m1, m2);
    m1 = fminf(m1, p.x);
    m2 = n2;
    n2 = __builtin_amdgcn_fmed3f(p.y, m1, m2);
    m1 = fminf(m1, p.y);
    m2 = n2;
  }
  float ds = sqrtf(fmaxf(m1, EPSF)) + sqrtf(fmaxf(m2, EPSF));
  dsum[g] = ds;

  float v = ds;
#pragma unroll
  for (int off = 32; off > 0; off >>= 1) v += __shfl_down(v, off, 64);
  __shared__ float warp_sums[BLOCK / 64];
  if ((threadIdx.x & 63) == 0) warp_sums[threadIdx.x >> 6] = v;
  __syncthreads();
  if (threadIdx.x == 0) {
    float t = 0.0f;
#pragma unroll
    for (int w = 0; w < BLOCK / 64; w++) t += warp_sums[w];
    partial[blockIdx.x] = t;
  }
}

// loss: single block of 1024 threads.
#define LBLK 1024
#define NPART (BN / BLOCK)          // 128 (merge grid size)
#define PPB (NPART / BB)            // 32 partials per batch
__global__ __launch_bounds__(LBLK) void loss_kernel(
    const float* __restrict__ dsum, const float* __restrict__ partial,
    float* __restrict__ out) {
  __shared__ float s_avg[BB];
  // phase 1: parallel partial reduction. Threads 0..127 each load one
  // partial; 32 consecutive partials belong to one batch -> width-32 shuffle.
  if (threadIdx.x < NPART) {
    float v = partial[threadIdx.x];
#pragma unroll
    for (int off = 16; off > 0; off >>= 1) v += __shfl_down(v, off, 32);
    if ((threadIdx.x & 31) == 0) s_avg[threadIdx.x >> 5] = v * (ALPHA / NN);
  }
  __syncthreads();

  // phase 2: vectorized thresholded sum over all BN points.
  const float4* d4 = (const float4*)dsum;
  float acc = 0.0f;
#pragma unroll
  for (int it = 0; it < BN / (LBLK * 4); it++) {
    int idx = it * LBLK + threadIdx.x;     // float4 index
    float4 v = d4[idx];
    float thr = s_avg[idx >> 11];          // 2048 float4 per batch
    acc += (v.x > thr) ? v.x : 0.0f;
    acc += (v.y > thr) ? v.y : 0.0f;
    acc += (v.z > thr) ? v.z : 0.0f;
    acc += (v.w > thr) ? v.w : 0.0f;
  }
#pragma unroll
  for (int off = 32; off > 0; off >>= 1) acc += __shfl_down(acc, off, 64);
  __shared__ float warp_sums[LBLK / 64];
  if ((threadIdx.x & 63) == 0) warp_sums[threadIdx.x >> 6] = acc;
  __syncthreads();
  if (threadIdx.x == 0) {
    float t = 0.0f;
#pragma unroll
    for (int w = 0; w < LBLK / 64; w++) t += warp_sums[w];
    out[0] = t;
  }
}

template <int NSEG>
static void run(const float* xyz, float* out, void* d_ws, hipStream_t stream) {
  float2* pairs = (float2*)d_ws;
  float* dsum = (float*)(pairs + (size_t)NSEG * BN);
  float* partial = dsum + BN;
  int grid1 = BB * (NN / QB) * NSEG;
  knn_kernel<NSEG><<<grid1, BLOCK, 0, stream>>>(xyz, pairs);
  merge_kernel<NSEG><<<BN / BLOCK, BLOCK, 0, stream>>>(pairs, dsum, partial);
  loss_kernel<<<1, LBLK, 0, stream>>>(dsum, partial, out);
}

extern "C" void kernel_launch(void* const* d_in, const int* in_sizes, int n_in,
                              void* d_out, int out_size, void* d_ws,
                              size_t ws_size, hipStream_t stream) {
  const float* xyz = (const float*)d_in[0];
  float* out = (float*)d_out;

  auto need = [](int nseg) {
    return (size_t)nseg * BN * sizeof(float2) + BN * sizeof(float) +
           NPART * sizeof(float);
  };
  if (ws_size >= need(32)) {
    run<32>(xyz, out, d_ws, stream);
  } else if (ws_size >= need(16)) {
    run<16>(xyz, out, d_ws, stream);
  } else {
    run<8>(xyz, out, d_ws, stream);
  }
}